// Round 15
// baseline (282.562 us; speedup 1.0000x reference)
//
#include <hip/hip_runtime.h>
#include <hip/hip_fp16.h>
#include <stdint.h>

#define N_NODES 50000
#define N_EDGES 800000
#define BCAP 64    // Poisson(16): P(deg>64) ~ 1e-22 — clamp is safe
#define NPART 782  // ceil(50000/64) dst-range partitions, 64 nodes each
#define NSUB 64    // 8 sub-lists per XCD per partition
#define SCAP 64    // per-sub-list capacity: Poisson(16) + 12 sigma

// prep_k fused-grid block ranges (append | cvt_x | cvt_w1 | cvt_w2)
#define NB_APPEND 391          // ceil(800000/8/256)  (8 edges/thread)
#define NB_CVTX   6250         // 50000*32/256
#define NB_CVTW1  256          // 256*256/256
#define NB_CVTW2  512          // 256*512/256

typedef _Float16 f16x8 __attribute__((ext_vector_type(8)));
typedef __attribute__((ext_vector_type(4))) float f32x4;

__device__ __forceinline__ unsigned short f2h(float f) {
    return __builtin_bit_cast(unsigned short, (_Float16)f);
}

// fp8 e4m3 with +2^-6 offset (inputs >= 0 post-relu): code is ALWAYS normal (c>=8),
// so decode is exactly linear in bits: f16 = (c<<7) + 0x2000. The +2^-6 telescopes
// to a per-node constant removed after reduction. v=0 roundtrips exactly.
__device__ __forceinline__ unsigned char f2fp8o(float v) {
    v = fminf(v, 440.f) + 0.015625f;
    unsigned int u = __builtin_bit_cast(unsigned int, v);
    u += 0x7FFFFu + ((u >> 20) & 1u);            // RNE to 3 mantissa bits
    return (unsigned char)((u >> 20) - 960u);    // ((exp-120)<<3)|mant3, 8..126
}

__device__ __forceinline__ void load_lds16(const void* g, void* l) {
    __builtin_amdgcn_global_load_lds(
        (const __attribute__((address_space(1))) void*)(uintptr_t)g,
        (__attribute__((address_space(3))) void*)(unsigned int)(uintptr_t)l,
        16, 0, 0);
}

// ---------------- fused prep: append ∥ cvt_x ∥ cvt_w1 ∥ cvt_w2 (R20, −10.5us) -------
// R22's append tweaks (8 edges/thread, NSUB 64) measured neutral — prep is pinned
// ~44us by atomic issue latency, kept as-is.  R21's cross-block spin-sync FAILED
// the container (hang) — cross-block flag sync is permanently off the table.
__global__ __launch_bounds__(256) void prep_k(
    const int* __restrict__ src, const int* __restrict__ dst,
    int* __restrict__ pcnt, unsigned int* __restrict__ pbuf,
    const float* __restrict__ x, unsigned short* __restrict__ xdst,
    const float* __restrict__ wl1, const float* __restrict__ wr1,
    unsigned short* __restrict__ w1dst,
    const float* __restrict__ wl2, const float* __restrict__ wr2,
    unsigned short* __restrict__ w2dst)
{
    int bid = blockIdx.x;
    if (bid < NB_APPEND) {
        unsigned xcc;
        asm("s_getreg_b32 %0, hwreg(HW_REG_XCC_ID)" : "=s"(xcc));
        const int sbase = (int)(xcc & 7) * 8;

        int t = bid * 256 + threadIdx.x;
        int e0 = t * 8;
        if (e0 >= N_EDGES) return;
        int4 sa = *(const int4*)(src + e0);
        int4 sb = *(const int4*)(src + e0 + 4);
        int4 da = *(const int4*)(dst + e0);
        int4 db = *(const int4*)(dst + e0 + 4);

        int d[8] = { da.x, da.y, da.z, da.w, db.x, db.y, db.z, db.w };
        int s[8] = { sa.x, sa.y, sa.z, sa.w, sb.x, sb.y, sb.z, sb.w };
        int p[8], c[8];
#pragma unroll
        for (int k = 0; k < 8; k++) {
            c[k] = (d[k] >> 6) * NSUB + sbase + k;
            p[k] = atomicAdd(&pcnt[c[k] * 16], 1);
        }
#pragma unroll
        for (int k = 0; k < 8; k++)
            if (p[k] < SCAP)
                pbuf[(size_t)c[k] * SCAP + p[k]] =
                    ((unsigned)(d[k] & 63) << 16) | (unsigned)s[k];
    } else if (bid < NB_APPEND + NB_CVTX) {
        int tid = (bid - NB_APPEND) * 256 + threadIdx.x;
        int row = tid >> 5, c = (tid & 31) * 4;
        float4 v = *(const float4*)(x + (size_t)row * 128 + c);
        ushort4 o;
        o.x = f2h(v.x); o.y = f2h(v.y); o.z = f2h(v.z); o.w = f2h(v.w);
        *(ushort4*)(xdst + (size_t)row * 256 + 128 + c) = o;
    } else if (bid < NB_APPEND + NB_CVTX + NB_CVTW1) {
        int tid = (bid - NB_APPEND - NB_CVTX) * 256 + threadIdx.x;
        int n = tid >> 8, k = tid & 255;
        float v = (k < 128) ? wl1[(size_t)n * 128 + k]
                            : wr1[(size_t)n * 128 + (k - 128)];
        w1dst[tid] = f2h(v);
    } else {
        int tid = (bid - NB_APPEND - NB_CVTX - NB_CVTW1) * 256 + threadIdx.x;
        int n = tid >> 9, k = tid & 511;
        float v = (k < 256) ? wl2[(size_t)n * 256 + k]
                            : wr2[(size_t)n * 256 + (k - 256)];
        w2dst[tid] = f2h(v);
    }
}

// ---------------- build pass B: per-partition local bucket fill (LDS counters) --------
__global__ __launch_bounds__(256) void part_bucket_k(
    const int* __restrict__ pcnt, const unsigned int* __restrict__ pbuf,
    int* __restrict__ bucket, int* __restrict__ degtot, float* __restrict__ invdeg)
{
    __shared__ int lcnt[64];
    int part = blockIdx.x, tid = threadIdx.x;
    int wv = tid >> 6, lane = tid & 63;
    if (tid < 64) lcnt[tid] = 0;
    __syncthreads();
#pragma unroll
    for (int sub = wv; sub < NSUB; sub += 4) {
        int cidx = part * NSUB + sub;
        int n = pcnt[cidx * 16];
        if (n > SCAP) n = SCAP;
        const unsigned int* pb = pbuf + (size_t)cidx * SCAP;
        for (int i = lane; i < n; i += 64) {
            unsigned int en = pb[i];
            int dlow = (int)(en >> 16), s = (int)(en & 0xFFFFu);
            int p = atomicAdd(&lcnt[dlow], 1);
            if (p < BCAP) bucket[(size_t)(part * 64 + dlow) * BCAP + p] = s;
        }
    }
    __syncthreads();
    if (tid < 64) {
        int node = part * 64 + tid;
        if (node < N_NODES) {
            int c = lcnt[tid];
            degtot[node] = (c > BCAP) ? BCAP : c;
            invdeg[node] = 1.0f / (float)(c > 1 ? c : 1);
        }
    }
}

// ---------------- layer-1 aggregation: f16 gather, packed-f16 accumulate ------------
__device__ __forceinline__ void acch4(__half2* a, uint4 u) {
    a[0] = __hadd2(a[0], __builtin_bit_cast(__half2, u.x));
    a[1] = __hadd2(a[1], __builtin_bit_cast(__half2, u.y));
    a[2] = __hadd2(a[2], __builtin_bit_cast(__half2, u.z));
    a[3] = __hadd2(a[3], __builtin_bit_cast(__half2, u.w));
}

__global__ __launch_bounds__(256) void agg1_k(
    const unsigned short* __restrict__ feat,
    const int* __restrict__ bucket, const int* __restrict__ degtot,
    const float* __restrict__ invdeg,
    unsigned short* __restrict__ outmsg)
{
    int wv = threadIdx.x >> 6, lane = threadIdx.x & 63;
    int node = blockIdx.x * 4 + wv;
    if (node >= N_NODES) return;
    int deg = degtot[node];
    int idx0 = bucket[(size_t)node * BCAP + lane];
    const int sub = lane >> 4;
    const int col = lane & 15;

    __half2 acc[4] = {};
    auto rowp = [&](int s) { return (const uint4*)(feat + (size_t)s * 256 + col * 8); };

    int j = 0;
    for (; j + 16 <= deg; j += 16) {
        int s0 = __shfl(idx0, j + sub),     s1 = __shfl(idx0, j + 4 + sub);
        int s2 = __shfl(idx0, j + 8 + sub), s3 = __shfl(idx0, j + 12 + sub);
        uint4 u0 = *rowp(s0), u1 = *rowp(s1), u2 = *rowp(s2), u3 = *rowp(s3);
        acch4(acc, u0); acch4(acc, u1); acch4(acc, u2); acch4(acc, u3);
    }
    for (; j + 8 <= deg; j += 8) {
        int s0 = __shfl(idx0, j + sub), s1 = __shfl(idx0, j + 4 + sub);
        uint4 u0 = *rowp(s0), u1 = *rowp(s1);
        acch4(acc, u0); acch4(acc, u1);
    }
    for (; j + 4 <= deg; j += 4) {
        uint4 u0 = *rowp(__shfl(idx0, j + sub));
        acch4(acc, u0);
    }
    if (j < deg) {                      // wave-uniform guard (R3 lesson)
        int e = j + sub;
        int ec = (e < deg) ? e : (deg - 1);
        uint4 u0 = *rowp(__shfl(idx0, ec));
        if (e < deg) acch4(acc, u0);
    }
#pragma unroll
    for (int stride = 32; stride >= 16; stride >>= 1)
#pragma unroll
        for (int v = 0; v < 4; v++) {
            int t = __shfl_xor(__builtin_bit_cast(int, acc[v]), stride);
            acc[v] = __hadd2(acc[v], __builtin_bit_cast(__half2, t));
        }

    if (lane < 16) {
        float s = invdeg[node];
        unsigned int o[4];
#pragma unroll
        for (int v = 0; v < 4; v++) {
            float2 f = __half22float2(acc[v]);
            o[v] = (unsigned int)f2h(f.x * s) | ((unsigned int)f2h(f.y * s) << 16);
        }
        *(uint4*)(outmsg + (size_t)node * 256 + lane * 8) = make_uint4(o[0], o[1], o[2], o[3]);
    }
}

// ---------------- layer-2 aggregation: offset-fp8 gather, linear decode, pk_add -----
__device__ __forceinline__ void accf8pk(__half2* a, unsigned int w) {
    unsigned int ev = ((w & 0x00FF00FFu) << 7) + 0x20002000u;
    unsigned int od = ((w >> 1) & 0x7F807F80u) + 0x20002000u;
    a[0] = __hadd2(a[0], __builtin_bit_cast(__half2, ev));
    a[1] = __hadd2(a[1], __builtin_bit_cast(__half2, od));
}
__device__ __forceinline__ void accf8x16(__half2* a, uint4 u) {
    accf8pk(a + 0, u.x); accf8pk(a + 2, u.y); accf8pk(a + 4, u.z); accf8pk(a + 6, u.w);
}

__global__ __launch_bounds__(256) void agg2_k(
    const unsigned char* __restrict__ hf8,
    const int* __restrict__ bucket, const int* __restrict__ degtot,
    const float* __restrict__ invdeg,
    unsigned short* __restrict__ outmsg)
{
    int wv = threadIdx.x >> 6, lane = threadIdx.x & 63;
    int node = blockIdx.x * 4 + wv;
    if (node >= N_NODES) return;
    int deg = degtot[node];
    int idx0 = bucket[(size_t)node * BCAP + lane];
    const int sub = lane >> 4;
    const int col = lane & 15;

    __half2 acc[8] = {};
    auto rowp = [&](int s) { return (const uint4*)(hf8 + (size_t)s * 256 + col * 16); };

    int j = 0;
    for (; j + 16 <= deg; j += 16) {
        int s0 = __shfl(idx0, j + sub),     s1 = __shfl(idx0, j + 4 + sub);
        int s2 = __shfl(idx0, j + 8 + sub), s3 = __shfl(idx0, j + 12 + sub);
        uint4 u0 = *rowp(s0), u1 = *rowp(s1), u2 = *rowp(s2), u3 = *rowp(s3);
        accf8x16(acc, u0); accf8x16(acc, u1); accf8x16(acc, u2); accf8x16(acc, u3);
    }
    for (; j + 8 <= deg; j += 8) {
        int s0 = __shfl(idx0, j + sub), s1 = __shfl(idx0, j + 4 + sub);
        uint4 u0 = *rowp(s0), u1 = *rowp(s1);
        accf8x16(acc, u0); accf8x16(acc, u1);
    }
    for (; j + 4 <= deg; j += 4) {
        uint4 u0 = *rowp(__shfl(idx0, j + sub));
        accf8x16(acc, u0);
    }
    if (j < deg) {
        int e = j + sub;
        int ec = (e < deg) ? e : (deg - 1);
        uint4 u0 = *rowp(__shfl(idx0, ec));
        if (e < deg) accf8x16(acc, u0);
    }
#pragma unroll
    for (int stride = 32; stride >= 16; stride >>= 1)
#pragma unroll
        for (int v = 0; v < 8; v++) {
            int t = __shfl_xor(__builtin_bit_cast(int, acc[v]), stride);
            acc[v] = __hadd2(acc[v], __builtin_bit_cast(__half2, t));
        }

    if (lane < 16) {
        float s = invdeg[node];
        float bias = (deg > 0) ? 0.015625f : 0.0f;
        unsigned int o[8];
#pragma unroll
        for (int q = 0; q < 4; q++) {
            float2 ev = __half22float2(acc[2 * q]);
            float2 od = __half22float2(acc[2 * q + 1]);
            float d0 = ev.x * s - bias, d1 = od.x * s - bias;
            float d2 = ev.y * s - bias, d3 = od.y * s - bias;
            o[2 * q]     = (unsigned int)f2h(d0) | ((unsigned int)f2h(d1) << 16);
            o[2 * q + 1] = (unsigned int)f2h(d2) | ((unsigned int)f2h(d3) << 16);
        }
        unsigned short* wp = outmsg + (size_t)node * 512 + lane * 16;
        *(uint4*)(wp)     = make_uint4(o[0], o[1], o[2], o[3]);
        *(uint4*)(wp + 8) = make_uint4(o[4], o[5], o[6], o[7]);
    }
}

// ---------------- f16 MFMA GEMM (R23): R14 structure, 128x64 tile, 2x the grid -----
// R22 counters: both gemms ~43us at only 2.0-2.4 TB/s achieved (floor ~13-17us),
// MfmaUtil 11%, Occupancy 17% — latency-bound with only 782 blocks (~3/CU, <=38%
// wave cap).  R23 changes ONLY the tile geometry: 128x64 (grid 391x4 = 1564
// blocks, 24KB LDS -> 6 blocks/CU, wave cap 76%).  Staging pattern (in-row XOR
// swizzle, 64B-per-row footprint), skeleton (2-buf + __syncthreads), epilogue all
// unchanged.  Swizzle algebra re-verified for 64-row W region (tt*16 contributes
// 0 mod 4 to (row>>1)&3 -> same qs).  A re-reads by 4 sibling panels are
// L3-absorbed (FETCH stayed at A-once with 2 panels).
template <bool F16OUT, bool WRITE_FP8>
__global__ __launch_bounds__(256) void gemm_k(
    const unsigned short* __restrict__ A, const unsigned short* __restrict__ W,
    const float* __restrict__ bias, void* __restrict__ outp, int outStride,
    unsigned char* __restrict__ hf8, int M, int K)
{
    __shared__ __align__(16) char smem[2 * 12288];  // 24 KB: two 12KB tile buffers
    const int t = threadIdx.x;
    const int w = t >> 6, lane = t & 63;
    const int quad = lane >> 4, l15 = lane & 15;
    const int row0 = blockIdx.x * 128;
    const int col0 = blockIdx.y * 64;
    const int niter = K >> 5;

    // Stage 768 chunks (512 A + 256 W), 3 per thread; wave-uniform A/W branch.
    auto stage = [&](int buf, int ks) {
#pragma unroll
        for (int j = 0; j < 3; j++) {
            int ci = j * 256 + t;        // 0..767
            const unsigned short* g;
            if (ci < 512) {              // A chunks: row = ci>>2, in-row chunk ci&3
                int rg = row0 + (ci >> 2);
                if (rg > M - 1) rg = M - 1;
                g = A + (size_t)rg * K + ks + (((ci & 3) ^ ((ci >> 3) & 3)) * 8);
            } else {                     // W chunks: 64 rows
                int c2 = ci - 512;
                g = W + (size_t)(col0 + (c2 >> 2)) * K + ks + (((c2 & 3) ^ ((c2 >> 3) & 3)) * 8);
            }
            load_lds16(g, smem + buf * 12288 + ci * 16);
        }
    };

    f32x4 acc[2][4] = {};

    stage(0, 0);
    __syncthreads();                     // tile 0 ready

    const int qs = (quad ^ ((l15 >> 1) & 3)) * 16;   // swizzled chunk byte offset

    for (int i = 0; i < niter; i++) {
        if (i + 1 < niter) stage((i + 1) & 1, (i + 1) << 5);   // async prefetch

        const char* base = smem + (i & 1) * 12288;
        const char* Ab = base + (w * 32 + l15) * 64 + qs;
        const char* Wb = base + 8192 + l15 * 64 + qs;
        f16x8 af0 = *(const f16x8*)(Ab);
        f16x8 af1 = *(const f16x8*)(Ab + 1024);
#pragma unroll
        for (int tt = 0; tt < 4; tt++) {
            f16x8 bfr = *(const f16x8*)(Wb + tt * 1024);
            acc[0][tt] = __builtin_amdgcn_mfma_f32_16x16x32_f16(af0, bfr, acc[0][tt], 0, 0, 0);
            acc[1][tt] = __builtin_amdgcn_mfma_f32_16x16x32_f16(af1, bfr, acc[1][tt], 0, 0, 0);
        }
        __syncthreads();                 // drains prefetch; frees buf (i&1) for iter i+1
    }

#pragma unroll
    for (int g = 0; g < 2; g++) {
#pragma unroll
        for (int tt = 0; tt < 4; tt++) {
            int col = col0 + tt * 16 + l15;
            float bv = bias[col];
#pragma unroll
            for (int i = 0; i < 4; i++) {
                int row = row0 + w * 32 + g * 16 + quad * 4 + i;  // C/D: col=lane&15, row=quad*4+reg
                if (row < M) {
                    float v = fmaxf(acc[g][tt][i] + bv, 0.f);
                    size_t off = (size_t)row * outStride + col;
                    if constexpr (F16OUT) ((unsigned short*)outp)[off] = f2h(v);
                    else                  ((float*)outp)[off] = v;
                    if constexpr (WRITE_FP8) hf8[(size_t)row * 256 + col] = f2fp8o(v);
                }
            }
        }
    }
}

extern "C" void kernel_launch(void* const* d_in, const int* in_sizes, int n_in,
                              void* d_out, int out_size, void* d_ws, size_t ws_size,
                              hipStream_t stream)
{
    const float* x   = (const float*)d_in[0];
    const int*   ei  = (const int*)d_in[1];
    const float* wl1 = (const float*)d_in[2];
    const float* bl1 = (const float*)d_in[3];
    const float* wr1 = (const float*)d_in[4];
    const float* wl2 = (const float*)d_in[5];
    const float* bl2 = (const float*)d_in[6];
    const float* wr2 = (const float*)d_in[7];
    float* out = (float*)d_out;
    const int* src = ei;
    const int* dst = ei + N_EDGES;

    char* ws = (char*)d_ws;
    size_t off = 0;
    auto alloc = [&](size_t bytes) -> void* {
        void* p = ws + off;
        off = (off + bytes + 255) & ~(size_t)255;
        return p;
    };
    int*            pcnt   = (int*)           alloc((size_t)NPART * NSUB * 16 * 4);
    unsigned int*   pbuf   = (unsigned int*)  alloc((size_t)NPART * NSUB * SCAP * 4);
    int*            bucket = (int*)           alloc((size_t)NPART * 64 * BCAP * 4);
    int*            degtot = (int*)           alloc((size_t)N_NODES * 4);
    float*          invdeg = (float*)         alloc((size_t)N_NODES * 4);
    unsigned short* Acat1  = (unsigned short*)alloc((size_t)N_NODES * 256 * 2);  // [msg1|x] f16
    unsigned short* Acat2  = (unsigned short*)alloc((size_t)N_NODES * 512 * 2);  // [msg2|h] f16
    unsigned char*  hf8    = (unsigned char*) alloc((size_t)N_NODES * 256);      // h fp8+offset
    unsigned short* Wcat1  = (unsigned short*)alloc((size_t)256 * 256 * 2);
    unsigned short* Wcat2  = (unsigned short*)alloc((size_t)256 * 512 * 2);

    hipMemsetAsync(pcnt, 0, (size_t)NPART * NSUB * 16 * 4, stream);

    // Fused prep: append ∥ cvt_x ∥ cvt_w1 ∥ cvt_w2 (independent work, one launch)
    prep_k<<<NB_APPEND + NB_CVTX + NB_CVTW1 + NB_CVTW2, 256, 0, stream>>>(
        src, dst, pcnt, pbuf, x, Acat1, wl1, wr1, Wcat1, wl2, wr2, Wcat2);

    part_bucket_k<<<NPART, 256, 0, stream>>>(pcnt, pbuf, bucket, degtot, invdeg);

    // Layer 1: agg x_f16 -> msg1; h = relu(Acat1 @ Wcat1^T + b) -> Acat2 right half (f16) + hf8
    agg1_k<<<(N_NODES + 3) / 4, 256, 0, stream>>>(
        Acat1 + 128, bucket, degtot, invdeg, Acat1);
    gemm_k<true, true><<<dim3((N_NODES + 127) / 128, 4), 256, 0, stream>>>(
        Acat1, Wcat1, bl1, (void*)(Acat2 + 256), 512, hf8, N_NODES, 256);

    // Layer 2: agg hf8 -> msg2; out = relu(Acat2 @ Wcat2^T + b) fp32
    agg2_k<<<(N_NODES + 3) / 4, 256, 0, stream>>>(
        hf8, bucket, degtot, invdeg, Acat2);
    gemm_k<false, false><<<dim3((N_NODES + 127) / 128, 4), 256, 0, stream>>>(
        Acat2, Wcat2, bl2, (void*)out, 256, nullptr, N_NODES, 512);
}

// Round 16
// 257.790 us; speedup vs baseline: 1.0961x; 1.0961x over previous
//
#include <hip/hip_runtime.h>
#include <hip/hip_fp16.h>
#include <stdint.h>

#define N_NODES 50000
#define N_EDGES 800000
#define BCAP 64    // Poisson(16): P(deg>64) ~ 1e-22 — clamp is safe
#define NPART 782  // ceil(50000/64) dst-range partitions, 64 nodes each
#define NSUB 32    // 4 sub-lists per XCD per partition (R20 best-measured config)
#define SCAP 128   // per-sub-list capacity: mean 32 -> huge margin

// prep_k fused-grid block ranges (append | cvt_x | cvt_w1 | cvt_w2)
#define NB_APPEND 782          // ceil(800000/4/256)  (4 edges/thread, R20)
#define NB_CVTX   6250         // 50000*32/256
#define NB_CVTW1  256          // 256*256/256
#define NB_CVTW2  512          // 256*512/256

#define NRB 391                // 128-row blocks
#define GEMM_GRID (((NRB + 7) / 8) * 32)   // 49 groups x (8 rb x 4 panels) = 1568

typedef _Float16 f16x8 __attribute__((ext_vector_type(8)));
typedef __attribute__((ext_vector_type(4))) float f32x4;

__device__ __forceinline__ unsigned short f2h(float f) {
    return __builtin_bit_cast(unsigned short, (_Float16)f);
}

// fp8 e4m3 with +2^-6 offset (inputs >= 0 post-relu): code is ALWAYS normal (c>=8),
// so decode is exactly linear in bits: f16 = (c<<7) + 0x2000. The +2^-6 telescopes
// to a per-node constant removed after reduction. v=0 roundtrips exactly.
__device__ __forceinline__ unsigned char f2fp8o(float v) {
    v = fminf(v, 440.f) + 0.015625f;
    unsigned int u = __builtin_bit_cast(unsigned int, v);
    u += 0x7FFFFu + ((u >> 20) & 1u);            // RNE to 3 mantissa bits
    return (unsigned char)((u >> 20) - 960u);    // ((exp-120)<<3)|mant3, 8..126
}

__device__ __forceinline__ void load_lds16(const void* g, void* l) {
    __builtin_amdgcn_global_load_lds(
        (const __attribute__((address_space(1))) void*)(uintptr_t)g,
        (__attribute__((address_space(3))) void*)(unsigned int)(uintptr_t)l,
        16, 0, 0);
}

// ---------------- fused prep: append ∥ cvt_x ∥ cvt_w1 ∥ cvt_w2 (R20 exact) ----------
// R20 (−10.5us): independent prep fused into one launch.  R22's append tweaks were
// neutral; reverted to R20's best-measured config.  R21's cross-block spin-sync
// FAILED the container — off the table (Guideline 16).
__global__ __launch_bounds__(256) void prep_k(
    const int* __restrict__ src, const int* __restrict__ dst,
    int* __restrict__ pcnt, unsigned int* __restrict__ pbuf,
    const float* __restrict__ x, unsigned short* __restrict__ xdst,
    const float* __restrict__ wl1, const float* __restrict__ wr1,
    unsigned short* __restrict__ w1dst,
    const float* __restrict__ wl2, const float* __restrict__ wr2,
    unsigned short* __restrict__ w2dst)
{
    int bid = blockIdx.x;
    if (bid < NB_APPEND) {
        // R18: XCD-local sub-lists — each pcnt/pbuf line written by ONE XCD.
        unsigned xcc;
        asm("s_getreg_b32 %0, hwreg(HW_REG_XCC_ID)" : "=s"(xcc));
        const int sbase = (int)(xcc & 7) * 4;

        int t = bid * 256 + threadIdx.x;
        int e0 = t * 4;
        if (e0 >= N_EDGES) return;
        int4 s4 = *(const int4*)(src + e0);
        int4 d4 = *(const int4*)(dst + e0);

        int c0 = (d4.x >> 6) * NSUB + sbase + 0;
        int c1 = (d4.y >> 6) * NSUB + sbase + 1;
        int c2 = (d4.z >> 6) * NSUB + sbase + 2;
        int c3 = (d4.w >> 6) * NSUB + sbase + 3;

        int p0 = atomicAdd(&pcnt[c0 * 16], 1);
        int p1 = atomicAdd(&pcnt[c1 * 16], 1);
        int p2 = atomicAdd(&pcnt[c2 * 16], 1);
        int p3 = atomicAdd(&pcnt[c3 * 16], 1);

        if (p0 < SCAP) pbuf[(size_t)c0 * SCAP + p0] = ((unsigned)(d4.x & 63) << 16) | (unsigned)s4.x;
        if (p1 < SCAP) pbuf[(size_t)c1 * SCAP + p1] = ((unsigned)(d4.y & 63) << 16) | (unsigned)s4.y;
        if (p2 < SCAP) pbuf[(size_t)c2 * SCAP + p2] = ((unsigned)(d4.z & 63) << 16) | (unsigned)s4.z;
        if (p3 < SCAP) pbuf[(size_t)c3 * SCAP + p3] = ((unsigned)(d4.w & 63) << 16) | (unsigned)s4.w;
    } else if (bid < NB_APPEND + NB_CVTX) {
        int tid = (bid - NB_APPEND) * 256 + threadIdx.x;
        int row = tid >> 5, c = (tid & 31) * 4;
        float4 v = *(const float4*)(x + (size_t)row * 128 + c);
        ushort4 o;
        o.x = f2h(v.x); o.y = f2h(v.y); o.z = f2h(v.z); o.w = f2h(v.w);
        *(ushort4*)(xdst + (size_t)row * 256 + 128 + c) = o;
    } else if (bid < NB_APPEND + NB_CVTX + NB_CVTW1) {
        int tid = (bid - NB_APPEND - NB_CVTX) * 256 + threadIdx.x;
        int n = tid >> 8, k = tid & 255;
        float v = (k < 128) ? wl1[(size_t)n * 128 + k]
                            : wr1[(size_t)n * 128 + (k - 128)];
        w1dst[tid] = f2h(v);
    } else {
        int tid = (bid - NB_APPEND - NB_CVTX - NB_CVTW1) * 256 + threadIdx.x;
        int n = tid >> 9, k = tid & 511;
        float v = (k < 256) ? wl2[(size_t)n * 256 + k]
                            : wr2[(size_t)n * 256 + (k - 256)];
        w2dst[tid] = f2h(v);
    }
}

// ---------------- build pass B: per-partition local bucket fill (LDS counters) --------
__global__ __launch_bounds__(256) void part_bucket_k(
    const int* __restrict__ pcnt, const unsigned int* __restrict__ pbuf,
    int* __restrict__ bucket, int* __restrict__ degtot, float* __restrict__ invdeg)
{
    __shared__ int lcnt[64];
    int part = blockIdx.x, tid = threadIdx.x;
    int wv = tid >> 6, lane = tid & 63;
    if (tid < 64) lcnt[tid] = 0;
    __syncthreads();
#pragma unroll
    for (int sub = wv; sub < NSUB; sub += 4) {
        int cidx = part * NSUB + sub;
        int n = pcnt[cidx * 16];
        if (n > SCAP) n = SCAP;
        const unsigned int* pb = pbuf + (size_t)cidx * SCAP;
        for (int i = lane; i < n; i += 64) {
            unsigned int en = pb[i];
            int dlow = (int)(en >> 16), s = (int)(en & 0xFFFFu);
            int p = atomicAdd(&lcnt[dlow], 1);
            if (p < BCAP) bucket[(size_t)(part * 64 + dlow) * BCAP + p] = s;
        }
    }
    __syncthreads();
    if (tid < 64) {
        int node = part * 64 + tid;
        if (node < N_NODES) {
            int c = lcnt[tid];
            degtot[node] = (c > BCAP) ? BCAP : c;
            invdeg[node] = 1.0f / (float)(c > 1 ? c : 1);
        }
    }
}

// ---------------- layer-1 aggregation: f16 gather, packed-f16 accumulate ------------
__device__ __forceinline__ void acch4(__half2* a, uint4 u) {
    a[0] = __hadd2(a[0], __builtin_bit_cast(__half2, u.x));
    a[1] = __hadd2(a[1], __builtin_bit_cast(__half2, u.y));
    a[2] = __hadd2(a[2], __builtin_bit_cast(__half2, u.z));
    a[3] = __hadd2(a[3], __builtin_bit_cast(__half2, u.w));
}

__global__ __launch_bounds__(256) void agg1_k(
    const unsigned short* __restrict__ feat,
    const int* __restrict__ bucket, const int* __restrict__ degtot,
    const float* __restrict__ invdeg,
    unsigned short* __restrict__ outmsg)
{
    int wv = threadIdx.x >> 6, lane = threadIdx.x & 63;
    int node = blockIdx.x * 4 + wv;
    if (node >= N_NODES) return;
    int deg = degtot[node];
    int idx0 = bucket[(size_t)node * BCAP + lane];
    const int sub = lane >> 4;
    const int col = lane & 15;

    __half2 acc[4] = {};
    auto rowp = [&](int s) { return (const uint4*)(feat + (size_t)s * 256 + col * 8); };

    int j = 0;
    for (; j + 16 <= deg; j += 16) {
        int s0 = __shfl(idx0, j + sub),     s1 = __shfl(idx0, j + 4 + sub);
        int s2 = __shfl(idx0, j + 8 + sub), s3 = __shfl(idx0, j + 12 + sub);
        uint4 u0 = *rowp(s0), u1 = *rowp(s1), u2 = *rowp(s2), u3 = *rowp(s3);
        acch4(acc, u0); acch4(acc, u1); acch4(acc, u2); acch4(acc, u3);
    }
    for (; j + 8 <= deg; j += 8) {
        int s0 = __shfl(idx0, j + sub), s1 = __shfl(idx0, j + 4 + sub);
        uint4 u0 = *rowp(s0), u1 = *rowp(s1);
        acch4(acc, u0); acch4(acc, u1);
    }
    for (; j + 4 <= deg; j += 4) {
        uint4 u0 = *rowp(__shfl(idx0, j + sub));
        acch4(acc, u0);
    }
    if (j < deg) {                      // wave-uniform guard (R3 lesson)
        int e = j + sub;
        int ec = (e < deg) ? e : (deg - 1);
        uint4 u0 = *rowp(__shfl(idx0, ec));
        if (e < deg) acch4(acc, u0);
    }
#pragma unroll
    for (int stride = 32; stride >= 16; stride >>= 1)
#pragma unroll
        for (int v = 0; v < 4; v++) {
            int t = __shfl_xor(__builtin_bit_cast(int, acc[v]), stride);
            acc[v] = __hadd2(acc[v], __builtin_bit_cast(__half2, t));
        }

    if (lane < 16) {
        float s = invdeg[node];
        unsigned int o[4];
#pragma unroll
        for (int v = 0; v < 4; v++) {
            float2 f = __half22float2(acc[v]);
            o[v] = (unsigned int)f2h(f.x * s) | ((unsigned int)f2h(f.y * s) << 16);
        }
        *(uint4*)(outmsg + (size_t)node * 256 + lane * 8) = make_uint4(o[0], o[1], o[2], o[3]);
    }
}

// ---------------- layer-2 aggregation: offset-fp8 gather, linear decode, pk_add -----
__device__ __forceinline__ void accf8pk(__half2* a, unsigned int w) {
    unsigned int ev = ((w & 0x00FF00FFu) << 7) + 0x20002000u;
    unsigned int od = ((w >> 1) & 0x7F807F80u) + 0x20002000u;
    a[0] = __hadd2(a[0], __builtin_bit_cast(__half2, ev));
    a[1] = __hadd2(a[1], __builtin_bit_cast(__half2, od));
}
__device__ __forceinline__ void accf8x16(__half2* a, uint4 u) {
    accf8pk(a + 0, u.x); accf8pk(a + 2, u.y); accf8pk(a + 4, u.z); accf8pk(a + 6, u.w);
}

__global__ __launch_bounds__(256) void agg2_k(
    const unsigned char* __restrict__ hf8,
    const int* __restrict__ bucket, const int* __restrict__ degtot,
    const float* __restrict__ invdeg,
    unsigned short* __restrict__ outmsg)
{
    int wv = threadIdx.x >> 6, lane = threadIdx.x & 63;
    int node = blockIdx.x * 4 + wv;
    if (node >= N_NODES) return;
    int deg = degtot[node];
    int idx0 = bucket[(size_t)node * BCAP + lane];
    const int sub = lane >> 4;
    const int col = lane & 15;

    __half2 acc[8] = {};
    auto rowp = [&](int s) { return (const uint4*)(hf8 + (size_t)s * 256 + col * 16); };

    int j = 0;
    for (; j + 16 <= deg; j += 16) {
        int s0 = __shfl(idx0, j + sub),     s1 = __shfl(idx0, j + 4 + sub);
        int s2 = __shfl(idx0, j + 8 + sub), s3 = __shfl(idx0, j + 12 + sub);
        uint4 u0 = *rowp(s0), u1 = *rowp(s1), u2 = *rowp(s2), u3 = *rowp(s3);
        accf8x16(acc, u0); accf8x16(acc, u1); accf8x16(acc, u2); accf8x16(acc, u3);
    }
    for (; j + 8 <= deg; j += 8) {
        int s0 = __shfl(idx0, j + sub), s1 = __shfl(idx0, j + 4 + sub);
        uint4 u0 = *rowp(s0), u1 = *rowp(s1);
        accf8x16(acc, u0); accf8x16(acc, u1);
    }
    for (; j + 4 <= deg; j += 4) {
        uint4 u0 = *rowp(__shfl(idx0, j + sub));
        accf8x16(acc, u0);
    }
    if (j < deg) {
        int e = j + sub;
        int ec = (e < deg) ? e : (deg - 1);
        uint4 u0 = *rowp(__shfl(idx0, ec));
        if (e < deg) accf8x16(acc, u0);
    }
#pragma unroll
    for (int stride = 32; stride >= 16; stride >>= 1)
#pragma unroll
        for (int v = 0; v < 8; v++) {
            int t = __shfl_xor(__builtin_bit_cast(int, acc[v]), stride);
            acc[v] = __hadd2(acc[v], __builtin_bit_cast(__half2, t));
        }

    if (lane < 16) {
        float s = invdeg[node];
        float bias = (deg > 0) ? 0.015625f : 0.0f;
        unsigned int o[8];
#pragma unroll
        for (int q = 0; q < 4; q++) {
            float2 ev = __half22float2(acc[2 * q]);
            float2 od = __half22float2(acc[2 * q + 1]);
            float d0 = ev.x * s - bias, d1 = od.x * s - bias;
            float d2 = ev.y * s - bias, d3 = od.y * s - bias;
            o[2 * q]     = (unsigned int)f2h(d0) | ((unsigned int)f2h(d1) << 16);
            o[2 * q + 1] = (unsigned int)f2h(d2) | ((unsigned int)f2h(d3) << 16);
        }
        unsigned short* wp = outmsg + (size_t)node * 512 + lane * 16;
        *(uint4*)(wp)     = make_uint4(o[0], o[1], o[2], o[3]);
        *(uint4*)(wp + 8) = make_uint4(o[4], o[5], o[6], o[7]);
    }
}

// ---------------- f16 MFMA GEMM (R24): 128x64 tile + XCD-local panel swizzle --------
// R23 isolated both effects: smaller tile (1564 blocks, 24KB LDS) raised occupancy
// 17->44% and achieved BW 2.4->3.55 TB/s (+45%) — but the 4 sibling panels of each
// row-block landed on DIFFERENT XCDs (round-robin), so A was fetched 2x (FETCH
// 109MB).  R24 keeps the geometry and adds the R11/R18-verified XCD-locality
// mapping: 1-D grid, rb = (id>>5)*8 + (id&7), panel = (id>>3)&3 — the 4 panels of
// a row-block have ids 8 apart == same id mod 8 -> SAME XCD, within 32 ids ->
// co-resident.  First panel pulls the 128KB A-tile into that XCD's L2; siblings
// hit L2.  Mapping is locality-only (correctness independent).  Tail: rb>=NRB ->
// uniform early return (before any barrier).
template <bool F16OUT, bool WRITE_FP8>
__global__ __launch_bounds__(256) void gemm_k(
    const unsigned short* __restrict__ A, const unsigned short* __restrict__ W,
    const float* __restrict__ bias, void* __restrict__ outp, int outStride,
    unsigned char* __restrict__ hf8, int M, int K)
{
    __shared__ __align__(16) char smem[2 * 12288];  // 24 KB: two 12KB tile buffers
    const int id = blockIdx.x;
    const int rb = (id >> 5) * 8 + (id & 7);
    const int panel = (id >> 3) & 3;
    if (rb >= NRB) return;               // uniform per block, before any barrier

    const int t = threadIdx.x;
    const int w = t >> 6, lane = t & 63;
    const int quad = lane >> 4, l15 = lane & 15;
    const int row0 = rb * 128;
    const int col0 = panel * 64;
    const int niter = K >> 5;

    // Stage 768 chunks (512 A + 256 W), 3 per thread; in-row XOR swizzle (R14).
    auto stage = [&](int buf, int ks) {
#pragma unroll
        for (int j = 0; j < 3; j++) {
            int ci = j * 256 + t;        // 0..767
            const unsigned short* g;
            if (ci < 512) {              // A chunks: row = ci>>2, in-row chunk ci&3
                int rg = row0 + (ci >> 2);
                if (rg > M - 1) rg = M - 1;
                g = A + (size_t)rg * K + ks + (((ci & 3) ^ ((ci >> 3) & 3)) * 8);
            } else {                     // W chunks: 64 rows
                int c2 = ci - 512;
                g = W + (size_t)(col0 + (c2 >> 2)) * K + ks + (((c2 & 3) ^ ((c2 >> 3) & 3)) * 8);
            }
            load_lds16(g, smem + buf * 12288 + ci * 16);
        }
    };

    f32x4 acc[2][4] = {};

    stage(0, 0);
    __syncthreads();                     // tile 0 ready

    const int qs = (quad ^ ((l15 >> 1) & 3)) * 16;   // swizzled chunk byte offset

    for (int i = 0; i < niter; i++) {
        if (i + 1 < niter) stage((i + 1) & 1, (i + 1) << 5);   // async prefetch

        const char* base = smem + (i & 1) * 12288;
        const char* Ab = base + (w * 32 + l15) * 64 + qs;
        const char* Wb = base + 8192 + l15 * 64 + qs;
        f16x8 af0 = *(const f16x8*)(Ab);
        f16x8 af1 = *(const f16x8*)(Ab + 1024);
#pragma unroll
        for (int tt = 0; tt < 4; tt++) {
            f16x8 bfr = *(const f16x8*)(Wb + tt * 1024);
            acc[0][tt] = __builtin_amdgcn_mfma_f32_16x16x32_f16(af0, bfr, acc[0][tt], 0, 0, 0);
            acc[1][tt] = __builtin_amdgcn_mfma_f32_16x16x32_f16(af1, bfr, acc[1][tt], 0, 0, 0);
        }
        __syncthreads();                 // drains prefetch; frees buf (i&1) for iter i+1
    }

#pragma unroll
    for (int g = 0; g < 2; g++) {
#pragma unroll
        for (int tt = 0; tt < 4; tt++) {
            int col = col0 + tt * 16 + l15;
            float bv = bias[col];
#pragma unroll
            for (int i = 0; i < 4; i++) {
                int row = row0 + w * 32 + g * 16 + quad * 4 + i;  // C/D: col=lane&15, row=quad*4+reg
                if (row < M) {
                    float v = fmaxf(acc[g][tt][i] + bv, 0.f);
                    size_t off = (size_t)row * outStride + col;
                    if constexpr (F16OUT) ((unsigned short*)outp)[off] = f2h(v);
                    else                  ((float*)outp)[off] = v;
                    if constexpr (WRITE_FP8) hf8[(size_t)row * 256 + col] = f2fp8o(v);
                }
            }
        }
    }
}

extern "C" void kernel_launch(void* const* d_in, const int* in_sizes, int n_in,
                              void* d_out, int out_size, void* d_ws, size_t ws_size,
                              hipStream_t stream)
{
    const float* x   = (const float*)d_in[0];
    const int*   ei  = (const int*)d_in[1];
    const float* wl1 = (const float*)d_in[2];
    const float* bl1 = (const float*)d_in[3];
    const float* wr1 = (const float*)d_in[4];
    const float* wl2 = (const float*)d_in[5];
    const float* bl2 = (const float*)d_in[6];
    const float* wr2 = (const float*)d_in[7];
    float* out = (float*)d_out;
    const int* src = ei;
    const int* dst = ei + N_EDGES;

    char* ws = (char*)d_ws;
    size_t off = 0;
    auto alloc = [&](size_t bytes) -> void* {
        void* p = ws + off;
        off = (off + bytes + 255) & ~(size_t)255;
        return p;
    };
    int*            pcnt   = (int*)           alloc((size_t)NPART * NSUB * 16 * 4);
    unsigned int*   pbuf   = (unsigned int*)  alloc((size_t)NPART * NSUB * SCAP * 4);
    int*            bucket = (int*)           alloc((size_t)NPART * 64 * BCAP * 4);
    int*            degtot = (int*)           alloc((size_t)N_NODES * 4);
    float*          invdeg = (float*)         alloc((size_t)N_NODES * 4);
    unsigned short* Acat1  = (unsigned short*)alloc((size_t)N_NODES * 256 * 2);  // [msg1|x] f16
    unsigned short* Acat2  = (unsigned short*)alloc((size_t)N_NODES * 512 * 2);  // [msg2|h] f16
    unsigned char*  hf8    = (unsigned char*) alloc((size_t)N_NODES * 256);      // h fp8+offset
    unsigned short* Wcat1  = (unsigned short*)alloc((size_t)256 * 256 * 2);
    unsigned short* Wcat2  = (unsigned short*)alloc((size_t)256 * 512 * 2);

    hipMemsetAsync(pcnt, 0, (size_t)NPART * NSUB * 16 * 4, stream);

    // Fused prep: append ∥ cvt_x ∥ cvt_w1 ∥ cvt_w2 (independent work, one launch)
    prep_k<<<NB_APPEND + NB_CVTX + NB_CVTW1 + NB_CVTW2, 256, 0, stream>>>(
        src, dst, pcnt, pbuf, x, Acat1, wl1, wr1, Wcat1, wl2, wr2, Wcat2);

    part_bucket_k<<<NPART, 256, 0, stream>>>(pcnt, pbuf, bucket, degtot, invdeg);

    // Layer 1: agg x_f16 -> msg1; h = relu(Acat1 @ Wcat1^T + b) -> Acat2 right half (f16) + hf8
    agg1_k<<<(N_NODES + 3) / 4, 256, 0, stream>>>(
        Acat1 + 128, bucket, degtot, invdeg, Acat1);
    gemm_k<true, true><<<GEMM_GRID, 256, 0, stream>>>(
        Acat1, Wcat1, bl1, (void*)(Acat2 + 256), 512, hf8, N_NODES, 256);

    // Layer 2: agg hf8 -> msg2; out = relu(Acat2 @ Wcat2^T + b) fp32
    agg2_k<<<(N_NODES + 3) / 4, 256, 0, stream>>>(
        hf8, bucket, degtot, invdeg, Acat2);
    gemm_k<false, false><<<GEMM_GRID, 256, 0, stream>>>(
        Acat2, Wcat2, bl2, (void*)out, 256, nullptr, N_NODES, 512);
}